// Round 4
// baseline (3911.774 us; speedup 1.0000x reference)
//
#include <hip/hip_runtime.h>
#include <math.h>

// B=256, T=2048, H=150. Sequential GRU, relu'd hidden, scalar linear head.
// 1 block per batch element (256 blocks = 256 CUs), 512 threads.
//
// Structure is EXACTLY the R1 kernel that passed at absmax 4.9e-4 (thread j
// < 450 computes the full 150-elem dot for row j; h broadcast via one
// ds_read_b128 per thread + v_readlane->SGPR->v_fmac; same accumulator
// split a0..a3 stride-4, same bias placement). ONE change: the weight row
// lives in 150 INDIVIDUALLY-NAMED scalar floats (constant indices only,
// never address-taken) instead of float w[152] -- R1/R2's array/ext-vector
// forms were demoted to scratch (VGPR_Count=92 -> 600B/thread/step scratch
// reload -> L2-bound ~5000 cyc/step, matching the measured 4640).
// __launch_bounds__(512,2): 256-VGPR cap, 2 waves/SIMD, 1 block/CU.

#define BB 256
#define TT 2048
#define HH 150
#define H3 450

__device__ __forceinline__ float rl(float v, int l) {
    return __uint_as_float(__builtin_amdgcn_readlane(__float_as_uint(v), l));
}

__global__ __launch_bounds__(512, 2) void gru_seq_kernel(
    const float* __restrict__ input,   // [B,T]
    const float* __restrict__ W_ih,    // [450,1]
    const float* __restrict__ W_hh,    // [450,150]
    const float* __restrict__ b_ih,    // [450]
    const float* __restrict__ b_hh,    // [450]
    const float* __restrict__ W_lin,   // [1,150]
    const float* __restrict__ b_lin,   // [1]
    float* __restrict__ out)           // [B,T]
{
    const int b    = blockIdx.x;
    const int tid  = threadIdx.x;
    const int lane = tid & 63;

    __shared__ float  xrow[TT];       // 8 KB: whole input row
    __shared__ float4 h4[64];         // h[0..149] zero-padded to 256 floats
    __shared__ float  pre[H3 + 2];
    __shared__ float  ypart[4];

    // ---- prologue -------------------------------------------------------
    ((float4*)xrow)[tid] = ((const float4*)(input + (size_t)b * TT))[tid];
    if (tid < 64) h4[tid] = make_float4(0.f, 0.f, 0.f, 0.f);
    if (tid < 4)  ypart[tid] = 0.f;

    // Weight row -> 150 named scalars. Threads >= 450 load row 449 (results
    // discarded by the `if (tid < H3)` guard on the pre[] store).
    const int row = (tid < H3) ? tid : (H3 - 1);
    const float* wr = W_hh + row * HH;
#define LW(i) float w##i = wr[i];
    LW(0)   LW(1)   LW(2)   LW(3)   LW(4)   LW(5)   LW(6)   LW(7)
    LW(8)   LW(9)   LW(10)  LW(11)  LW(12)  LW(13)  LW(14)  LW(15)
    LW(16)  LW(17)  LW(18)  LW(19)  LW(20)  LW(21)  LW(22)  LW(23)
    LW(24)  LW(25)  LW(26)  LW(27)  LW(28)  LW(29)  LW(30)  LW(31)
    LW(32)  LW(33)  LW(34)  LW(35)  LW(36)  LW(37)  LW(38)  LW(39)
    LW(40)  LW(41)  LW(42)  LW(43)  LW(44)  LW(45)  LW(46)  LW(47)
    LW(48)  LW(49)  LW(50)  LW(51)  LW(52)  LW(53)  LW(54)  LW(55)
    LW(56)  LW(57)  LW(58)  LW(59)  LW(60)  LW(61)  LW(62)  LW(63)
    LW(64)  LW(65)  LW(66)  LW(67)  LW(68)  LW(69)  LW(70)  LW(71)
    LW(72)  LW(73)  LW(74)  LW(75)  LW(76)  LW(77)  LW(78)  LW(79)
    LW(80)  LW(81)  LW(82)  LW(83)  LW(84)  LW(85)  LW(86)  LW(87)
    LW(88)  LW(89)  LW(90)  LW(91)  LW(92)  LW(93)  LW(94)  LW(95)
    LW(96)  LW(97)  LW(98)  LW(99)  LW(100) LW(101) LW(102) LW(103)
    LW(104) LW(105) LW(106) LW(107) LW(108) LW(109) LW(110) LW(111)
    LW(112) LW(113) LW(114) LW(115) LW(116) LW(117) LW(118) LW(119)
    LW(120) LW(121) LW(122) LW(123) LW(124) LW(125) LW(126) LW(127)
    LW(128) LW(129) LW(130) LW(131) LW(132) LW(133) LW(134) LW(135)
    LW(136) LW(137) LW(138) LW(139) LW(140) LW(141) LW(142) LW(143)
    LW(144) LW(145) LW(146) LW(147) LW(148) LW(149)
    const float w150 = 0.f, w151 = 0.f;       // pad; h[150..151]==0 anyway
    const float bhh = (tid < H3) ? b_hh[tid] : 0.f;

    float wih_r = 0.f, wih_z = 0.f, wih_n = 0.f;
    float bih_r = 0.f, bih_z = 0.f, bih_n = 0.f, wlin = 0.f;
    if (tid < HH) {
        wih_r = W_ih[tid];          bih_r = b_ih[tid];
        wih_z = W_ih[HH + tid];     bih_z = b_ih[HH + tid];
        wih_n = W_ih[2 * HH + tid]; bih_n = b_ih[2 * HH + tid];
        wlin  = W_lin[tid];
    }
    const float blin = b_lin[0];
    float hreg = 0.f;
    float* outb = out + (size_t)b * TT;

    __syncthreads();

    // ---- recurrence -----------------------------------------------------
    for (int t = 0; t < TT; ++t) {
        // phase 1: h . W_hh[row]. hv lane q holds h[4q..4q+3]; readlane
        // broadcasts to SGPR feeding v_fmac against resident weight regs.
        // Accumulation order IDENTICAL to the passing R1 kernel.
        float4 hv = h4[lane];
        float a0 = 0.f, a1 = 0.f, a2 = 0.f, a3 = 0.f;
#define D4(Q, A, B, C, D) { \
        float hx = rl(hv.x, Q), hy = rl(hv.y, Q), hz = rl(hv.z, Q), hw = rl(hv.w, Q); \
        a0 = fmaf(hx, w##A, a0); \
        a1 = fmaf(hy, w##B, a1); \
        a2 = fmaf(hz, w##C, a2); \
        a3 = fmaf(hw, w##D, a3); }
        D4( 0,   0,   1,   2,   3) D4( 1,   4,   5,   6,   7)
        D4( 2,   8,   9,  10,  11) D4( 3,  12,  13,  14,  15)
        D4( 4,  16,  17,  18,  19) D4( 5,  20,  21,  22,  23)
        D4( 6,  24,  25,  26,  27) D4( 7,  28,  29,  30,  31)
        D4( 8,  32,  33,  34,  35) D4( 9,  36,  37,  38,  39)
        D4(10,  40,  41,  42,  43) D4(11,  44,  45,  46,  47)
        D4(12,  48,  49,  50,  51) D4(13,  52,  53,  54,  55)
        D4(14,  56,  57,  58,  59) D4(15,  60,  61,  62,  63)
        D4(16,  64,  65,  66,  67) D4(17,  68,  69,  70,  71)
        D4(18,  72,  73,  74,  75) D4(19,  76,  77,  78,  79)
        D4(20,  80,  81,  82,  83) D4(21,  84,  85,  86,  87)
        D4(22,  88,  89,  90,  91) D4(23,  92,  93,  94,  95)
        D4(24,  96,  97,  98,  99) D4(25, 100, 101, 102, 103)
        D4(26, 104, 105, 106, 107) D4(27, 108, 109, 110, 111)
        D4(28, 112, 113, 114, 115) D4(29, 116, 117, 118, 119)
        D4(30, 120, 121, 122, 123) D4(31, 124, 125, 126, 127)
        D4(32, 128, 129, 130, 131) D4(33, 132, 133, 134, 135)
        D4(34, 136, 137, 138, 139) D4(35, 140, 141, 142, 143)
        D4(36, 144, 145, 146, 147) D4(37, 148, 149, 150, 151)
        if (tid < H3) pre[tid] = (a0 + a1) + (a2 + a3) + bhh;
        __syncthreads();

        // phase 2: gates + hidden update (threads 0..149) -- identical to R1
        float yc = 0.f;
        if (tid < HH) {
            float x  = xrow[t];
            float gr = fmaf(x, wih_r, bih_r) + pre[tid];
            float gz = fmaf(x, wih_z, bih_z) + pre[HH + tid];
            float hn = pre[2 * HH + tid];
            float r  = 1.f / (1.f + __expf(-gr));
            float z  = 1.f / (1.f + __expf(-gz));
            float ta = fmaf(x, wih_n, bih_n) + r * hn;
            ta = fminf(fmaxf(ta, -15.f), 15.f);
            float e  = __expf(2.f * ta);
            float n  = (e - 1.f) / (e + 1.f);        // tanh
            float hnew = fmaf(z, hreg - n, n);       // (1-z)*n + z*h
            hnew = fmaxf(hnew, 0.f);                 // relu
            hreg = hnew;
            ((float*)h4)[tid] = hnew;
            yc = hnew * wlin;
        }
        if (tid < 192) {
            #pragma unroll
            for (int off = 32; off >= 1; off >>= 1)
                yc += __shfl_down(yc, off, 64);
            if (lane == 0) ypart[tid >> 6] = yc;
        }
        __syncthreads();
        if (tid == 0) outb[t] = ypart[0] + ypart[1] + ypart[2] + blin;
    }
}

extern "C" void kernel_launch(void* const* d_in, const int* in_sizes, int n_in,
                              void* d_out, int out_size, void* d_ws, size_t ws_size,
                              hipStream_t stream) {
    const float* input = (const float*)d_in[0];
    const float* W_ih  = (const float*)d_in[1];
    const float* W_hh  = (const float*)d_in[2];
    const float* b_ih  = (const float*)d_in[3];
    const float* b_hh  = (const float*)d_in[4];
    const float* W_lin = (const float*)d_in[5];
    const float* b_lin = (const float*)d_in[6];
    float* out = (float*)d_out;

    gru_seq_kernel<<<dim3(BB), dim3(512), 0, stream>>>(
        input, W_ih, W_hh, b_ih, b_hh, W_lin, b_lin, out);
}